// Round 1
// 709.281 us; speedup vs baseline: 1.6054x; 1.6054x over previous
//
#include <hip/hip_runtime.h>
#include <hip/hip_bf16.h>

constexpr int U_N = 100000;
constexpr int I_N = 50000;
constexpr int KDIM = 64;
constexpr float EPSF = 1e-12f;

// bucketed CSR build params
constexpr int RPB = 256;        // rows per bucket (dst & 255 fits in u8)
constexpr int BSHIFT = 8;       // bucket = dst >> 8
constexpr int CH = 4096;        // edges per partition chunk

typedef float f4 __attribute__((ext_vector_type(4)));
typedef unsigned short u16;

__device__ inline f4 ld4(const float* p) { return *(const f4*)p; }

// pack two f32 -> two bf16 (RNE) in one uint32
__device__ inline unsigned pack_bf16(float a, float b) {
    unsigned ua = __float_as_uint(a);
    unsigned ub = __float_as_uint(b);
    ua += 0x7fffu + ((ua >> 16) & 1u);
    ub += 0x7fffu + ((ub >> 16) & 1u);
    return (ua >> 16) | (ub & 0xffff0000u);
}

// unpack 8 bf16 (uint4) -> 8 f32
__device__ inline void bf8_to_f32(uint4 u, float* f) {
    unsigned w0 = u.x, w1 = u.y, w2 = u.z, w3 = u.w;
    f[0] = __uint_as_float(w0 << 16);  f[1] = __uint_as_float(w0 & 0xffff0000u);
    f[2] = __uint_as_float(w1 << 16);  f[3] = __uint_as_float(w1 & 0xffff0000u);
    f[4] = __uint_as_float(w2 << 16);  f[5] = __uint_as_float(w2 & 0xffff0000u);
    f[6] = __uint_as_float(w3 << 16);  f[7] = __uint_as_float(w3 & 0xffff0000u);
}

// ---------------- bucketed CSR build ----------------
// Pass 1: per-bucket histogram (bucket = dst>>8). LDS-aggregated.
__global__ void bhist_k(const int* __restrict__ dst, int* __restrict__ cnt, int E, int NB) {
    __shared__ int h[1024];
    int t = threadIdx.x;  // 256 threads
    for (int i = t; i < 1024; i += 256) h[i] = 0;
    __syncthreads();
    int stride = gridDim.x * 256 * 4;
    for (int i = (blockIdx.x * 256 + t) * 4; i < E; i += stride) {
        if (i + 4 <= E) {
            int4 d = *(const int4*)(dst + i);
            atomicAdd(&h[d.x >> BSHIFT], 1);
            atomicAdd(&h[d.y >> BSHIFT], 1);
            atomicAdd(&h[d.z >> BSHIFT], 1);
            atomicAdd(&h[d.w >> BSHIFT], 1);
        } else {
            for (int k = i; k < E; ++k) atomicAdd(&h[dst[k] >> BSHIFT], 1);
        }
    }
    __syncthreads();
    for (int i = t; i < NB; i += 256) if (h[i]) atomicAdd(&cnt[i], h[i]);
}

// Pass 2: exclusive scan of bucket counts -> base[], cursor[] (NB <= 1024, one WG)
__global__ void bscan_k(const int* __restrict__ cnt, int* __restrict__ base,
                        int* __restrict__ cur, int NB) {
    __shared__ int s[1024];
    int t = threadIdx.x;  // 1024
    int c = (t < NB) ? cnt[t] : 0;
    s[t] = c;
    __syncthreads();
    for (int off = 1; off < 1024; off <<= 1) {
        int v = s[t] + ((t >= off) ? s[t - off] : 0);
        __syncthreads();
        s[t] = v;
        __syncthreads();
    }
    int ex = s[t] - c;
    if (t < NB) { base[t] = ex; cur[t] = ex; }
    if (t == NB - 1) base[NB] = s[t];
}

// Pass 3: partition edges into buckets. LDS-staged so global writes are
// contiguous runs per (WG, bucket). Emits (src,w) pairs + low-8-bits-of-dst.
__global__ __launch_bounds__(1024) void bpart_k(
        const int* __restrict__ src, const int* __restrict__ dst,
        const float* __restrict__ w, int* __restrict__ gcur,
        int2* __restrict__ pairs, unsigned char* __restrict__ dlo,
        int E, int NB) {
    __shared__ int hist[1024];          // per-bucket count, then local cursor
    __shared__ int sA[1024];            // scan
    __shared__ int rb[1024];            // global run base per bucket
    __shared__ int2 stp[CH];            // staged (src, w)
    __shared__ unsigned stg[CH];        // staged gaddr | (dlo<<24)  (E < 2^24)
    int t = threadIdx.x;
    int nch = (E + CH - 1) / CH;
    for (int c = blockIdx.x; c < nch; c += gridDim.x) {
        int cb = c * CH;
        int n = min(CH, E - cb);
        hist[t] = 0;
        __syncthreads();
        int esrc[4], ew[4], ebkt[4], edlo[4];
        bool ev[4];
#pragma unroll
        for (int k = 0; k < 4; ++k) {
            int j = k * 1024 + t;
            ev[k] = j < n;
            if (ev[k]) {
                int i = cb + j;
                int d = dst[i];
                esrc[k] = src[i];
                ew[k] = __float_as_int(w[i]);
                ebkt[k] = d >> BSHIFT;
                edlo[k] = d & (RPB - 1);
                atomicAdd(&hist[ebkt[k]], 1);
            }
        }
        __syncthreads();
        int cnt_t = hist[t];
        sA[t] = cnt_t;
        __syncthreads();
        for (int off = 1; off < 1024; off <<= 1) {
            int v = sA[t] + ((t >= off) ? sA[t - off] : 0);
            __syncthreads();
            sA[t] = v;
            __syncthreads();
        }
        sA[t] -= cnt_t;  // own-element only: inclusive -> exclusive, no race
        if (t < NB && cnt_t > 0) rb[t] = atomicAdd(&gcur[t], cnt_t);
        hist[t] = 0;     // becomes local placement cursor
        __syncthreads();
#pragma unroll
        for (int k = 0; k < 4; ++k) {
            if (ev[k]) {
                int b = ebkt[k];
                int local = atomicAdd(&hist[b], 1);
                int pos = sA[b] + local;
                stp[pos] = make_int2(esrc[k], ew[k]);
                stg[pos] = (unsigned)(rb[b] + local) | ((unsigned)edlo[k] << 24);
            }
        }
        __syncthreads();
#pragma unroll
        for (int k = 0; k < 4; ++k) {
            int p = k * 1024 + t;
            if (p < n) {
                unsigned g = stg[p];
                unsigned ga = g & 0xFFFFFFu;
                pairs[ga] = stp[p];
                dlo[ga] = (unsigned char)(g >> 24);
            }
        }
        __syncthreads();
    }
}

// Pass 4: per-bucket counting sort. One WG per bucket; scatter region is
// ~64KB written by a single WG (single XCD) -> lines merge in its L2.
// Also emits global row starts (replaces global hist+scan chain).
__global__ __launch_bounds__(1024) void bfill_k(
        const int* __restrict__ base, const int2* __restrict__ pairs,
        const unsigned char* __restrict__ dlo, int2* __restrict__ e2,
        int* __restrict__ start, int NB, int Nrows) {
    __shared__ int hist[RPB];
    __shared__ int pos[RPB + 1];
    int t = threadIdx.x;  // 1024
    for (int b = blockIdx.x; b < NB; b += gridDim.x) {
        int gb = base[b];
        int cnt = base[b + 1] - gb;
        if (t < RPB) hist[t] = 0;
        __syncthreads();
        for (int i = t; i < cnt; i += 1024) atomicAdd(&hist[dlo[gb + i]], 1);
        __syncthreads();
        if (t < RPB) pos[t] = hist[t];
        __syncthreads();
        for (int off = 1; off < RPB; off <<= 1) {
            int v = 0;
            if (t < RPB) v = pos[t] + ((t >= off) ? pos[t - off] : 0);
            __syncthreads();
            if (t < RPB) pos[t] = v;
            __syncthreads();
        }
        int myv = 0;
        if (t < RPB) myv = (t == 0) ? 0 : pos[t - 1];
        __syncthreads();
        if (t < RPB) pos[t] = myv;
        if (t == 0) pos[RPB] = cnt;
        __syncthreads();
        // row starts: start[r0+j] = gb + exclusive_scan[j]; continuity across
        // buckets holds because base[] is the exclusive scan of bucket counts.
        int r0 = b * RPB;
        if (t <= RPB) {
            int row = r0 + t;
            if (row <= Nrows) start[row] = gb + pos[t];
        }
        __syncthreads();
        for (int i = t; i < cnt; i += 1024) {
            int r = dlo[gb + i];
            int p = atomicAdd(&pos[r], 1);
            e2[gb + p] = pairs[gb + i];
        }
        __syncthreads();
    }
}

// ---------------- compute ----------------

__device__ inline float group8_sum(float v) {
    v += __shfl_xor(v, 1, 64);
    v += __shfl_xor(v, 2, 64);
    v += __shfl_xor(v, 4, 64);
    return v;
}

// Gather-accumulate one CSR row from bf16 table.
// Wave layout: g = lane>>3 (8 edge slots), l = lane&7 (8 features each, 16B load).
__device__ inline void spmm_row_bf(const int2* __restrict__ e2, int j0, int j1,
                                   const u16* __restrict__ x, int g, int l,
                                   float a[8]) {
    float a0[8] = {0, 0, 0, 0, 0, 0, 0, 0};
    float a1[8] = {0, 0, 0, 0, 0, 0, 0, 0};
    int j = j0;
    for (; j + 16 <= j1; j += 16) {
        int2 ea = e2[j + g];
        int2 eb = e2[j + 8 + g];
        uint4 ua = *(const uint4*)(x + (size_t)ea.x * KDIM + l * 8);
        uint4 ub = *(const uint4*)(x + (size_t)eb.x * KDIM + l * 8);
        float wa = __int_as_float(ea.y), wb = __int_as_float(eb.y);
        float fa[8], fb[8];
        bf8_to_f32(ua, fa);
        bf8_to_f32(ub, fb);
#pragma unroll
        for (int c = 0; c < 8; ++c) {
            a0[c] += wa * fa[c];
            a1[c] += wb * fb[c];
        }
    }
    for (; j < j1; j += 8) {
        if (j + g < j1) {
            int2 ea = e2[j + g];
            uint4 ua = *(const uint4*)(x + (size_t)ea.x * KDIM + l * 8);
            float wa = __int_as_float(ea.y);
            float fa[8];
            bf8_to_f32(ua, fa);
#pragma unroll
            for (int c = 0; c < 8; ++c) a0[c] += wa * fa[c];
        }
    }
#pragma unroll
    for (int c = 0; c < 8; ++c) {
        float v = a0[c] + a1[c];
        v += __shfl_xor(v, 8, 64);
        v += __shfl_xor(v, 16, 64);
        v += __shfl_xor(v, 32, 64);
        a[c] = v;
    }
}

// cur(bf16) = acc(f32) = concat(Gu, Gi); one thread per 8 elements
__global__ void ego_init8(const float* __restrict__ Gu, const float* __restrict__ Gi,
                          u16* __restrict__ cur, float* __restrict__ acc, int n8) {
    int i = blockIdx.x * blockDim.x + threadIdx.x;
    if (i >= n8) return;
    const int nu8 = U_N * (KDIM / 8);
    const float* p = (i < nu8) ? Gu + (size_t)i * 8 : Gi + (size_t)(i - nu8) * 8;
    f4 v0 = ld4(p);
    f4 v1 = ld4(p + 4);
    uint4 pk;
    pk.x = pack_bf16(v0.x, v0.y);
    pk.y = pack_bf16(v0.z, v0.w);
    pk.z = pack_bf16(v1.x, v1.y);
    pk.w = pack_bf16(v1.z, v1.w);
    *(uint4*)(cur + (size_t)i * 8) = pk;
    *(f4*)(acc + (size_t)i * 8) = v0;
    *(f4*)(acc + (size_t)i * 8 + 4) = v1;
}

// f32 -> bf16 bulk convert, 8 elems/thread
__global__ void cvt_bf8(const float* __restrict__ in, u16* __restrict__ out, int n8) {
    int i = blockIdx.x * blockDim.x + threadIdx.x;
    if (i >= n8) return;
    f4 v0 = ld4(in + (size_t)i * 8);
    f4 v1 = ld4(in + (size_t)i * 8 + 4);
    uint4 pk;
    pk.x = pack_bf16(v0.x, v0.y);
    pk.y = pack_bf16(v0.z, v0.w);
    pk.z = pack_bf16(v1.x, v1.y);
    pk.w = pack_bf16(v1.z, v1.w);
    *(uint4*)(out + (size_t)i * 8) = pk;
}

// pull SPMM, bf16 in -> bf16 out (gis hop 1)
__global__ void spmm_pull_bf(const int* __restrict__ start, const int2* __restrict__ e2,
                             const u16* __restrict__ x, u16* __restrict__ y, int nrows) {
    const int lane = threadIdx.x & 63;
    const int g = lane >> 3, l = lane & 7;
    const int r = (blockIdx.x * blockDim.x + threadIdx.x) >> 6;
    if (r >= nrows) return;
    float a[8];
    spmm_row_bf(e2, start[r], start[r + 1], x, g, l, a);
    if (g == 0) {
        uint4 pk;
        pk.x = pack_bf16(a[0], a[1]);
        pk.y = pack_bf16(a[2], a[3]);
        pk.z = pack_bf16(a[4], a[5]);
        pk.w = pack_bf16(a[6], a[7]);
        *(uint4*)(y + (size_t)r * KDIM + l * 8) = pk;
    }
}

// pull SPMM, bf16 in -> f32 out (gis hop 2)
__global__ void spmm_pull_f32(const int* __restrict__ start, const int2* __restrict__ e2,
                              const u16* __restrict__ x, float* __restrict__ y, int nrows) {
    const int lane = threadIdx.x & 63;
    const int g = lane >> 3, l = lane & 7;
    const int r = (blockIdx.x * blockDim.x + threadIdx.x) >> 6;
    if (r >= nrows) return;
    float a[8];
    spmm_row_bf(e2, start[r], start[r + 1], x, g, l, a);
    if (g == 0) {
        float* yp = y + (size_t)r * KDIM + l * 8;
        *(f4*)yp = f4{a[0], a[1], a[2], a[3]};
        *(f4*)(yp + 4) = f4{a[4], a[5], a[6], a[7]};
    }
}

// pull SPMM + l2norm; normalized row -> cur (bf16), acc += normalized (f32)
__global__ void spmm_pull_norm(const int* __restrict__ start, const int2* __restrict__ e2,
                               const u16* __restrict__ x, u16* __restrict__ cur,
                               float* __restrict__ acc, int nrows) {
    const int lane = threadIdx.x & 63;
    const int g = lane >> 3, l = lane & 7;
    const int r = (blockIdx.x * blockDim.x + threadIdx.x) >> 6;
    if (r >= nrows) return;
    float a[8];
    spmm_row_bf(e2, start[r], start[r + 1], x, g, l, a);
    float loc = 0.f;
#pragma unroll
    for (int c = 0; c < 8; ++c) loc += a[c] * a[c];
    float ss = group8_sum(loc);
    float inv = 1.f / fmaxf(sqrtf(ss), EPSF);
    if (g == 0) {
        uint4 pk;
        pk.x = pack_bf16(a[0] * inv, a[1] * inv);
        pk.y = pack_bf16(a[2] * inv, a[3] * inv);
        pk.z = pack_bf16(a[4] * inv, a[5] * inv);
        pk.w = pack_bf16(a[6] * inv, a[7] * inv);
        *(uint4*)(cur + (size_t)r * KDIM + l * 8) = pk;
        float* ap = acc + (size_t)r * KDIM + l * 8;
        f4 o0 = ld4(ap);
        f4 o1 = ld4(ap + 4);
        o0 += f4{a[0] * inv, a[1] * inv, a[2] * inv, a[3] * inv};
        o1 += f4{a[4] * inv, a[5] * inv, a[6] * inv, a[7] * inv};
        *(f4*)ap = o0;
        *(f4*)(ap + 4) = o1;
    }
}

// Last UI layer fused with finalize:
// out = (acc + l2norm(spmm_row)) / 4  (+ l2norm(gis) for item rows), f32 out
__global__ void spmm_pull_norm_final(const int* __restrict__ start, const int2* __restrict__ e2,
                                     const u16* __restrict__ x, const float* __restrict__ gis,
                                     float* __restrict__ acc_out, int nrows) {
    const int lane = threadIdx.x & 63;
    const int g = lane >> 3, l = lane & 7;
    const int r = (blockIdx.x * blockDim.x + threadIdx.x) >> 6;
    if (r >= nrows) return;
    float a[8];
    spmm_row_bf(e2, start[r], start[r + 1], x, g, l, a);
    float loc = 0.f;
#pragma unroll
    for (int c = 0; c < 8; ++c) loc += a[c] * a[c];
    float ss = group8_sum(loc);
    float inv = 1.f / fmaxf(sqrtf(ss), EPSF);
    if (g != 0) return;
    float* ap = acc_out + (size_t)r * KDIM + l * 8;
    f4 v0 = (ld4(ap) + f4{a[0] * inv, a[1] * inv, a[2] * inv, a[3] * inv}) * 0.25f;
    f4 v1 = (ld4(ap + 4) + f4{a[4] * inv, a[5] * inv, a[6] * inv, a[7] * inv}) * 0.25f;
    if (r >= U_N) {
        const float* gp = gis + (size_t)(r - U_N) * KDIM + l * 8;
        f4 g0 = ld4(gp);
        f4 g1 = ld4(gp + 4);
        float loc2 = g0.x * g0.x + g0.y * g0.y + g0.z * g0.z + g0.w * g0.w
                   + g1.x * g1.x + g1.y * g1.y + g1.z * g1.z + g1.w * g1.w;
        float ss2 = group8_sum(loc2);
        float inv2 = 1.f / fmaxf(sqrtf(ss2), EPSF);
        v0 += g0 * inv2;
        v1 += g1 * inv2;
    }
    *(f4*)ap = v0;
    *(f4*)(ap + 4) = v1;
}

extern "C" void kernel_launch(void* const* d_in, const int* in_sizes, int n_in,
                              void* d_out, int out_size, void* d_ws, size_t ws_size,
                              hipStream_t stream) {
    const float* Gu     = (const float*)d_in[0];
    const float* Gi     = (const float*)d_in[1];
    const float* Gis    = (const float*)d_in[2];
    const float* ii_w   = (const float*)d_in[3];
    const float* ui_w   = (const float*)d_in[4];
    const int*   ii_src = (const int*)d_in[5];
    const int*   ii_dst = (const int*)d_in[6];
    const int*   ui_src = (const int*)d_in[7];
    const int*   ui_dst = (const int*)d_in[8];
    const int E_II = in_sizes[5];
    const int E_UI = in_sizes[7];

    const int NR    = U_N + I_N;                     // 150000 rows
    const size_t NI = (size_t)I_N * KDIM;            // 3.2M elems
    const size_t NA = (size_t)NR * KDIM;             // 9.6M elems

    // ---- workspace layout (all segments 16B-aligned by construction) ----
    u16*  bufA = (u16*)d_ws;               // NA bf16 (19.2MB)
    u16*  bufB = bufA + NA;                // NA bf16
    u16*  gis0 = bufB + NA;                // NI bf16 (cvt of Gis)
    u16*  gisA = gis0 + NI;                // NI bf16
    float* gisB = (float*)(gisA + NI);     // NI f32
    int2*  ui_e = (int2*)(gisB + NI);      // E_UI
    int2*  ii_e = ui_e + E_UI;             // E_II
    int*   ui_start = (int*)(ii_e + E_II); // NR+1
    int*   ii_start = ui_start + (NR + 1); // I_N+1
    int*   bkt_cnt  = ii_start + (I_N + 1);// <=1024
    int*   bkt_base = bkt_cnt + 1024;      // <=1024+1
    int*   bkt_cur  = bkt_base + 1056;     // <=1024

    // CSR-build scratch reuses buffers that are dead until after the builds:
    // bufA+bufB = 38.4MB == E_UI*8B (pairs), gis0 = 6.4MB >= E_UI*1B (dlo)
    int2*          pairs_s = (int2*)bufA;
    unsigned char* dlo_s   = (unsigned char*)gis0;

    float* acc = (float*)d_out;            // f32 accumulator lives in d_out

    const int NB_UI = (NR + RPB - 1) / RPB;    // 586
    const int NB_II = (I_N + RPB - 1) / RPB;   // 196

    // ---- build UI CSR (bucketed counting sort by dst) ----
    hipMemsetAsync(bkt_cnt, 0, NB_UI * sizeof(int), stream);
    bhist_k<<<1024, 256, 0, stream>>>(ui_dst, bkt_cnt, E_UI, NB_UI);
    bscan_k<<<1, 1024, 0, stream>>>(bkt_cnt, bkt_base, bkt_cur, NB_UI);
    bpart_k<<<512, 1024, 0, stream>>>(ui_src, ui_dst, ui_w, bkt_cur, pairs_s, dlo_s, E_UI, NB_UI);
    bfill_k<<<256, 1024, 0, stream>>>(bkt_base, pairs_s, dlo_s, ui_e, ui_start, NB_UI, NR);

    // ---- build II CSR (same machinery, scratch reused) ----
    hipMemsetAsync(bkt_cnt, 0, NB_II * sizeof(int), stream);
    bhist_k<<<1024, 256, 0, stream>>>(ii_dst, bkt_cnt, E_II, NB_II);
    bscan_k<<<1, 1024, 0, stream>>>(bkt_cnt, bkt_base, bkt_cur, NB_II);
    bpart_k<<<512, 1024, 0, stream>>>(ii_src, ii_dst, ii_w, bkt_cur, pairs_s, dlo_s, E_II, NB_II);
    bfill_k<<<256, 1024, 0, stream>>>(bkt_base, pairs_s, dlo_s, ii_e, ii_start, NB_II, I_N);

    // ---- gis chain: gis0 = bf16(Gis); gisA = spmm(gis0); gisB = spmm(gisA) ----
    cvt_bf8<<<(int)((NI / 8 + 255) / 256), 256, 0, stream>>>(Gis, gis0, (int)(NI / 8));
    spmm_pull_bf<<<(I_N + 3) / 4, 256, 0, stream>>>(ii_start, ii_e, gis0, gisA, I_N);
    spmm_pull_f32<<<(I_N + 3) / 4, 256, 0, stream>>>(ii_start, ii_e, gisA, gisB, I_N);

    // ---- ego init: bufA(bf16) = acc(f32) = [Gu; Gi] ----
    ego_init8<<<(int)((NA / 8 + 255) / 256), 256, 0, stream>>>(Gu, Gi, bufA, acc, (int)(NA / 8));

    // ---- 3 UI layers (norm fused; last one fuses finalize) ----
    spmm_pull_norm<<<(NR + 3) / 4, 256, 0, stream>>>(ui_start, ui_e, bufA, bufB, acc, NR);
    spmm_pull_norm<<<(NR + 3) / 4, 256, 0, stream>>>(ui_start, ui_e, bufB, bufA, acc, NR);
    spmm_pull_norm_final<<<(NR + 3) / 4, 256, 0, stream>>>(ui_start, ui_e, bufA, gisB, acc, NR);
}

// Round 2
// 686.583 us; speedup vs baseline: 1.6585x; 1.0331x over previous
//
#include <hip/hip_runtime.h>
#include <hip/hip_bf16.h>

constexpr int U_N = 100000;
constexpr int I_N = 50000;
constexpr int KDIM = 64;
constexpr float EPSF = 1e-12f;

// bucketed CSR build params
constexpr int RPB = 256;        // rows per bucket (dst & 255 fits in u8)
constexpr int BSHIFT = 8;       // bucket = dst >> 8
constexpr int CH = 4096;        // edges per partition chunk

typedef float f4 __attribute__((ext_vector_type(4)));
typedef unsigned short u16;

__device__ inline f4 ld4(const float* p) { return *(const f4*)p; }

// pack two f32 -> two bf16 (RNE) in one uint32
__device__ inline unsigned pack_bf16(float a, float b) {
    unsigned ua = __float_as_uint(a);
    unsigned ub = __float_as_uint(b);
    ua += 0x7fffu + ((ua >> 16) & 1u);
    ub += 0x7fffu + ((ub >> 16) & 1u);
    return (ua >> 16) | (ub & 0xffff0000u);
}

// unpack 8 bf16 (uint4) -> 8 f32
__device__ inline void bf8_to_f32(uint4 u, float* f) {
    unsigned w0 = u.x, w1 = u.y, w2 = u.z, w3 = u.w;
    f[0] = __uint_as_float(w0 << 16);  f[1] = __uint_as_float(w0 & 0xffff0000u);
    f[2] = __uint_as_float(w1 << 16);  f[3] = __uint_as_float(w1 & 0xffff0000u);
    f[4] = __uint_as_float(w2 << 16);  f[5] = __uint_as_float(w2 & 0xffff0000u);
    f[6] = __uint_as_float(w3 << 16);  f[7] = __uint_as_float(w3 & 0xffff0000u);
}

// ---------------- bucketed CSR build ----------------
// Pass 1: per-bucket histogram (bucket = dst>>8). LDS-aggregated.
__global__ void bhist_k(const int* __restrict__ dst, int* __restrict__ cnt, int E, int NB) {
    __shared__ int h[1024];
    int t = threadIdx.x;  // 256 threads
    for (int i = t; i < 1024; i += 256) h[i] = 0;
    __syncthreads();
    int stride = gridDim.x * 256 * 4;
    for (int i = (blockIdx.x * 256 + t) * 4; i < E; i += stride) {
        if (i + 4 <= E) {
            int4 d = *(const int4*)(dst + i);
            atomicAdd(&h[d.x >> BSHIFT], 1);
            atomicAdd(&h[d.y >> BSHIFT], 1);
            atomicAdd(&h[d.z >> BSHIFT], 1);
            atomicAdd(&h[d.w >> BSHIFT], 1);
        } else {
            for (int k = i; k < E; ++k) atomicAdd(&h[dst[k] >> BSHIFT], 1);
        }
    }
    __syncthreads();
    for (int i = t; i < NB; i += 256) if (h[i]) atomicAdd(&cnt[i], h[i]);
}

// Pass 2: exclusive scan of bucket counts -> base[], cursor[] (NB <= 1024, one WG)
__global__ void bscan_k(const int* __restrict__ cnt, int* __restrict__ base,
                        int* __restrict__ cur, int NB) {
    __shared__ int s[1024];
    int t = threadIdx.x;  // 1024
    int c = (t < NB) ? cnt[t] : 0;
    s[t] = c;
    __syncthreads();
    for (int off = 1; off < 1024; off <<= 1) {
        int v = s[t] + ((t >= off) ? s[t - off] : 0);
        __syncthreads();
        s[t] = v;
        __syncthreads();
    }
    int ex = s[t] - c;
    if (t < NB) { base[t] = ex; cur[t] = ex; }
    if (t == NB - 1) base[NB] = s[t];
}

// Pass 3: partition edges into buckets. LDS-staged so global writes are
// contiguous runs per (WG, bucket). Emits (src,w) pairs + low-8-bits-of-dst.
__global__ __launch_bounds__(1024) void bpart_k(
        const int* __restrict__ src, const int* __restrict__ dst,
        const float* __restrict__ w, int* __restrict__ gcur,
        int2* __restrict__ pairs, unsigned char* __restrict__ dlo,
        int E, int NB) {
    __shared__ int hist[1024];          // per-bucket count, then local cursor
    __shared__ int sA[1024];            // scan
    __shared__ int rb[1024];            // global run base per bucket
    __shared__ int2 stp[CH];            // staged (src, w)
    __shared__ unsigned stg[CH];        // staged gaddr | (dlo<<24)  (E < 2^24)
    int t = threadIdx.x;
    int nch = (E + CH - 1) / CH;
    for (int c = blockIdx.x; c < nch; c += gridDim.x) {
        int cb = c * CH;
        int n = min(CH, E - cb);
        hist[t] = 0;
        __syncthreads();
        int esrc[4], ew[4], ebkt[4], edlo[4];
        bool ev[4];
#pragma unroll
        for (int k = 0; k < 4; ++k) {
            int j = k * 1024 + t;
            ev[k] = j < n;
            if (ev[k]) {
                int i = cb + j;
                int d = dst[i];
                esrc[k] = src[i];
                ew[k] = __float_as_int(w[i]);
                ebkt[k] = d >> BSHIFT;
                edlo[k] = d & (RPB - 1);
                atomicAdd(&hist[ebkt[k]], 1);
            }
        }
        __syncthreads();
        int cnt_t = hist[t];
        sA[t] = cnt_t;
        __syncthreads();
        for (int off = 1; off < 1024; off <<= 1) {
            int v = sA[t] + ((t >= off) ? sA[t - off] : 0);
            __syncthreads();
            sA[t] = v;
            __syncthreads();
        }
        sA[t] -= cnt_t;  // own-element only: inclusive -> exclusive, no race
        if (t < NB && cnt_t > 0) rb[t] = atomicAdd(&gcur[t], cnt_t);
        hist[t] = 0;     // becomes local placement cursor
        __syncthreads();
#pragma unroll
        for (int k = 0; k < 4; ++k) {
            if (ev[k]) {
                int b = ebkt[k];
                int local = atomicAdd(&hist[b], 1);
                int pos = sA[b] + local;
                stp[pos] = make_int2(esrc[k], ew[k]);
                stg[pos] = (unsigned)(rb[b] + local) | ((unsigned)edlo[k] << 24);
            }
        }
        __syncthreads();
#pragma unroll
        for (int k = 0; k < 4; ++k) {
            int p = k * 1024 + t;
            if (p < n) {
                unsigned g = stg[p];
                unsigned ga = g & 0xFFFFFFu;
                pairs[ga] = stp[p];
                dlo[ga] = (unsigned char)(g >> 24);
            }
        }
        __syncthreads();
    }
}

// Pass 4: per-bucket counting sort. One WG per bucket; scatter region is
// ~64KB written by a single WG (single XCD) -> lines merge in its L2.
// Also emits global row starts (replaces global hist+scan chain).
__global__ __launch_bounds__(1024) void bfill_k(
        const int* __restrict__ base, const int2* __restrict__ pairs,
        const unsigned char* __restrict__ dlo, int2* __restrict__ e2,
        int* __restrict__ start, int NB, int Nrows) {
    __shared__ int hist[RPB];
    __shared__ int pos[RPB + 1];
    int t = threadIdx.x;  // 1024
    for (int b = blockIdx.x; b < NB; b += gridDim.x) {
        int gb = base[b];
        int cnt = base[b + 1] - gb;
        if (t < RPB) hist[t] = 0;
        __syncthreads();
        for (int i = t; i < cnt; i += 1024) atomicAdd(&hist[dlo[gb + i]], 1);
        __syncthreads();
        if (t < RPB) pos[t] = hist[t];
        __syncthreads();
        for (int off = 1; off < RPB; off <<= 1) {
            int v = 0;
            if (t < RPB) v = pos[t] + ((t >= off) ? pos[t - off] : 0);
            __syncthreads();
            if (t < RPB) pos[t] = v;
            __syncthreads();
        }
        int myv = 0;
        if (t < RPB) myv = (t == 0) ? 0 : pos[t - 1];
        __syncthreads();
        if (t < RPB) pos[t] = myv;
        if (t == 0) pos[RPB] = cnt;
        __syncthreads();
        // row starts: start[r0+j] = gb + exclusive_scan[j]; continuity across
        // buckets holds because base[] is the exclusive scan of bucket counts.
        int r0 = b * RPB;
        if (t <= RPB) {
            int row = r0 + t;
            if (row <= Nrows) start[row] = gb + pos[t];
        }
        __syncthreads();
        for (int i = t; i < cnt; i += 1024) {
            int r = dlo[gb + i];
            int p = atomicAdd(&pos[r], 1);
            e2[gb + p] = pairs[gb + i];
        }
        __syncthreads();
    }
}

// ---------------- compute ----------------

__device__ inline float group8_sum(float v) {
    v += __shfl_xor(v, 1, 64);
    v += __shfl_xor(v, 2, 64);
    v += __shfl_xor(v, 4, 64);
    return v;
}

// Gather-accumulate one CSR row from bf16 table.
// Wave layout: g = lane>>3 (8 edge slots), l = lane&7 (8 features each, 16B load).
__device__ inline void spmm_row_bf(const int2* __restrict__ e2, int j0, int j1,
                                   const u16* __restrict__ x, int g, int l,
                                   float a[8]) {
    float a0[8] = {0, 0, 0, 0, 0, 0, 0, 0};
    float a1[8] = {0, 0, 0, 0, 0, 0, 0, 0};
    int j = j0;
    for (; j + 16 <= j1; j += 16) {
        int2 ea = e2[j + g];
        int2 eb = e2[j + 8 + g];
        uint4 ua = *(const uint4*)(x + (size_t)ea.x * KDIM + l * 8);
        uint4 ub = *(const uint4*)(x + (size_t)eb.x * KDIM + l * 8);
        float wa = __int_as_float(ea.y), wb = __int_as_float(eb.y);
        float fa[8], fb[8];
        bf8_to_f32(ua, fa);
        bf8_to_f32(ub, fb);
#pragma unroll
        for (int c = 0; c < 8; ++c) {
            a0[c] += wa * fa[c];
            a1[c] += wb * fb[c];
        }
    }
    for (; j < j1; j += 8) {
        if (j + g < j1) {
            int2 ea = e2[j + g];
            uint4 ua = *(const uint4*)(x + (size_t)ea.x * KDIM + l * 8);
            float wa = __int_as_float(ea.y);
            float fa[8];
            bf8_to_f32(ua, fa);
#pragma unroll
            for (int c = 0; c < 8; ++c) a0[c] += wa * fa[c];
        }
    }
#pragma unroll
    for (int c = 0; c < 8; ++c) {
        float v = a0[c] + a1[c];
        v += __shfl_xor(v, 8, 64);
        v += __shfl_xor(v, 16, 64);
        v += __shfl_xor(v, 32, 64);
        a[c] = v;
    }
}

// f32 -> bf16 bulk convert, 8 elems/thread
__global__ void cvt_bf8(const float* __restrict__ in, u16* __restrict__ out, int n8) {
    int i = blockIdx.x * blockDim.x + threadIdx.x;
    if (i >= n8) return;
    f4 v0 = ld4(in + (size_t)i * 8);
    f4 v1 = ld4(in + (size_t)i * 8 + 4);
    uint4 pk;
    pk.x = pack_bf16(v0.x, v0.y);
    pk.y = pack_bf16(v0.z, v0.w);
    pk.z = pack_bf16(v1.x, v1.y);
    pk.w = pack_bf16(v1.z, v1.w);
    *(uint4*)(out + (size_t)i * 8) = pk;
}

// pull SPMM, bf16 in -> bf16 out (gis hop 1)
__global__ void spmm_pull_bf(const int* __restrict__ start, const int2* __restrict__ e2,
                             const u16* __restrict__ x, u16* __restrict__ y, int nrows) {
    const int lane = threadIdx.x & 63;
    const int g = lane >> 3, l = lane & 7;
    const int r = (blockIdx.x * blockDim.x + threadIdx.x) >> 6;
    if (r >= nrows) return;
    float a[8];
    spmm_row_bf(e2, start[r], start[r + 1], x, g, l, a);
    if (g == 0) {
        uint4 pk;
        pk.x = pack_bf16(a[0], a[1]);
        pk.y = pack_bf16(a[2], a[3]);
        pk.z = pack_bf16(a[4], a[5]);
        pk.w = pack_bf16(a[6], a[7]);
        *(uint4*)(y + (size_t)r * KDIM + l * 8) = pk;
    }
}

// pull SPMM, bf16 in -> f32 out (gis hop 2)
__global__ void spmm_pull_f32(const int* __restrict__ start, const int2* __restrict__ e2,
                              const u16* __restrict__ x, float* __restrict__ y, int nrows) {
    const int lane = threadIdx.x & 63;
    const int g = lane >> 3, l = lane & 7;
    const int r = (blockIdx.x * blockDim.x + threadIdx.x) >> 6;
    if (r >= nrows) return;
    float a[8];
    spmm_row_bf(e2, start[r], start[r + 1], x, g, l, a);
    if (g == 0) {
        float* yp = y + (size_t)r * KDIM + l * 8;
        *(f4*)yp = f4{a[0], a[1], a[2], a[3]};
        *(f4*)(yp + 4) = f4{a[4], a[5], a[6], a[7]};
    }
}

// pull SPMM + l2norm; normalized row -> cur (bf16) ONLY (no accumulator RMW).
// The mean is reconstructed in the final kernel from the bf16 layer outputs.
__global__ void spmm_pull_norm_noacc(const int* __restrict__ start, const int2* __restrict__ e2,
                                     const u16* __restrict__ x, u16* __restrict__ cur,
                                     int nrows) {
    const int lane = threadIdx.x & 63;
    const int g = lane >> 3, l = lane & 7;
    const int r = (blockIdx.x * blockDim.x + threadIdx.x) >> 6;
    if (r >= nrows) return;
    float a[8];
    spmm_row_bf(e2, start[r], start[r + 1], x, g, l, a);
    float loc = 0.f;
#pragma unroll
    for (int c = 0; c < 8; ++c) loc += a[c] * a[c];
    float ss = group8_sum(loc);
    float inv = 1.f / fmaxf(sqrtf(ss), EPSF);
    if (g == 0) {
        uint4 pk;
        pk.x = pack_bf16(a[0] * inv, a[1] * inv);
        pk.y = pack_bf16(a[2] * inv, a[3] * inv);
        pk.z = pack_bf16(a[4] * inv, a[5] * inv);
        pk.w = pack_bf16(a[6] * inv, a[7] * inv);
        *(uint4*)(cur + (size_t)r * KDIM + l * 8) = pk;
    }
}

// Last UI layer fused with finalize:
// n3 = l2norm(spmm(n2));  out = (ego + n1 + n2 + n3)/4  (+ l2norm(gis) for items)
// ego read straight from Gu/Gi (f32 inputs), n1/n2 from the bf16 layer buffers.
__global__ void spmm_pull_norm_final(const int* __restrict__ start, const int2* __restrict__ e2,
                                     const u16* __restrict__ x,   // n2 (also gather table)
                                     const u16* __restrict__ n1,
                                     const float* __restrict__ Gu,
                                     const float* __restrict__ Gi,
                                     const float* __restrict__ gis,
                                     float* __restrict__ out, int nrows) {
    const int lane = threadIdx.x & 63;
    const int g = lane >> 3, l = lane & 7;
    const int r = (blockIdx.x * blockDim.x + threadIdx.x) >> 6;
    if (r >= nrows) return;
    float a[8];
    spmm_row_bf(e2, start[r], start[r + 1], x, g, l, a);
    float loc = 0.f;
#pragma unroll
    for (int c = 0; c < 8; ++c) loc += a[c] * a[c];
    float ss = group8_sum(loc);
    float inv = 1.f / fmaxf(sqrtf(ss), EPSF);
    if (g != 0) return;
    // ego from inputs (pure stream, never reused -> non-temporal)
    const float* ep = (r < U_N) ? Gu + (size_t)r * KDIM + l * 8
                                : Gi + (size_t)(r - U_N) * KDIM + l * 8;
    f4 e0 = __builtin_nontemporal_load((const f4*)ep);
    f4 e1 = __builtin_nontemporal_load((const f4*)(ep + 4));
    // n1, n2 rows (bf16, L3-hot: n2 is the gather table of this very kernel)
    uint4 u1 = *(const uint4*)(n1 + (size_t)r * KDIM + l * 8);
    uint4 u2 = *(const uint4*)(x + (size_t)r * KDIM + l * 8);
    float f1[8], f2[8];
    bf8_to_f32(u1, f1);
    bf8_to_f32(u2, f2);
    f4 v0 = (e0 + f4{f1[0], f1[1], f1[2], f1[3]} + f4{f2[0], f2[1], f2[2], f2[3]}
                + f4{a[0] * inv, a[1] * inv, a[2] * inv, a[3] * inv}) * 0.25f;
    f4 v1 = (e1 + f4{f1[4], f1[5], f1[6], f1[7]} + f4{f2[4], f2[5], f2[6], f2[7]}
                + f4{a[4] * inv, a[5] * inv, a[6] * inv, a[7] * inv}) * 0.25f;
    if (r >= U_N) {
        const float* gp = gis + (size_t)(r - U_N) * KDIM + l * 8;
        f4 g0 = ld4(gp);
        f4 g1 = ld4(gp + 4);
        float loc2 = g0.x * g0.x + g0.y * g0.y + g0.z * g0.z + g0.w * g0.w
                   + g1.x * g1.x + g1.y * g1.y + g1.z * g1.z + g1.w * g1.w;
        // only lanes 0..7 here; group8_sum works within this group
        float ss2 = group8_sum(loc2);
        float inv2 = 1.f / fmaxf(sqrtf(ss2), EPSF);
        v0 += g0 * inv2;
        v1 += g1 * inv2;
    }
    float* op = out + (size_t)r * KDIM + l * 8;
    __builtin_nontemporal_store(v0, (f4*)op);
    __builtin_nontemporal_store(v1, (f4*)(op + 4));
}

extern "C" void kernel_launch(void* const* d_in, const int* in_sizes, int n_in,
                              void* d_out, int out_size, void* d_ws, size_t ws_size,
                              hipStream_t stream) {
    const float* Gu     = (const float*)d_in[0];
    const float* Gi     = (const float*)d_in[1];
    const float* Gis    = (const float*)d_in[2];
    const float* ii_w   = (const float*)d_in[3];
    const float* ui_w   = (const float*)d_in[4];
    const int*   ii_src = (const int*)d_in[5];
    const int*   ii_dst = (const int*)d_in[6];
    const int*   ui_src = (const int*)d_in[7];
    const int*   ui_dst = (const int*)d_in[8];
    const int E_II = in_sizes[5];
    const int E_UI = in_sizes[7];

    const int NR    = U_N + I_N;                     // 150000 rows
    const size_t NI = (size_t)I_N * KDIM;            // 3.2M elems
    const size_t NA = (size_t)NR * KDIM;             // 9.6M elems

    // ---- workspace layout (all segments 16B-aligned by construction) ----
    u16*  bufA = (u16*)d_ws;               // NA bf16 (19.2MB)
    u16*  bufB = bufA + NA;                // NA bf16
    u16*  gis0 = bufB + NA;                // NI bf16 (cvt of Gis)
    u16*  gisA = gis0 + NI;                // NI bf16
    float* gisB = (float*)(gisA + NI);     // NI f32
    int2*  ui_e = (int2*)(gisB + NI);      // E_UI
    int2*  ii_e = ui_e + E_UI;             // E_II
    int*   ui_start = (int*)(ii_e + E_II); // NR+1
    int*   ii_start = ui_start + (NR + 1); // I_N+1
    int*   bkt_cnt  = ii_start + (I_N + 1);// <=1024
    int*   bkt_base = bkt_cnt + 1024;      // <=1024+1
    int*   bkt_cur  = bkt_base + 1056;     // <=1024

    // CSR-build scratch reuses buffers that are dead until after the builds:
    // bufA+bufB = 38.4MB == E_UI*8B (pairs), gis0 = 6.4MB >= E_UI*1B (dlo)
    int2*          pairs_s = (int2*)bufA;
    unsigned char* dlo_s   = (unsigned char*)gis0;

    float* out = (float*)d_out;

    const int NB_UI = (NR + RPB - 1) / RPB;    // 586
    const int NB_II = (I_N + RPB - 1) / RPB;   // 196

    // ---- build UI CSR (bucketed counting sort by dst) ----
    hipMemsetAsync(bkt_cnt, 0, NB_UI * sizeof(int), stream);
    bhist_k<<<1024, 256, 0, stream>>>(ui_dst, bkt_cnt, E_UI, NB_UI);
    bscan_k<<<1, 1024, 0, stream>>>(bkt_cnt, bkt_base, bkt_cur, NB_UI);
    bpart_k<<<512, 1024, 0, stream>>>(ui_src, ui_dst, ui_w, bkt_cur, pairs_s, dlo_s, E_UI, NB_UI);
    bfill_k<<<256, 1024, 0, stream>>>(bkt_base, pairs_s, dlo_s, ui_e, ui_start, NB_UI, NR);

    // ---- build II CSR (same machinery, scratch reused) ----
    hipMemsetAsync(bkt_cnt, 0, NB_II * sizeof(int), stream);
    bhist_k<<<1024, 256, 0, stream>>>(ii_dst, bkt_cnt, E_II, NB_II);
    bscan_k<<<1, 1024, 0, stream>>>(bkt_cnt, bkt_base, bkt_cur, NB_II);
    bpart_k<<<512, 1024, 0, stream>>>(ii_src, ii_dst, ii_w, bkt_cur, pairs_s, dlo_s, E_II, NB_II);
    bfill_k<<<256, 1024, 0, stream>>>(bkt_base, pairs_s, dlo_s, ii_e, ii_start, NB_II, I_N);

    // ---- gis chain: gis0 = bf16(Gis); gisA = spmm(gis0); gisB = spmm(gisA) ----
    cvt_bf8<<<(int)((NI / 8 + 255) / 256), 256, 0, stream>>>(Gis, gis0, (int)(NI / 8));
    spmm_pull_bf<<<(I_N + 3) / 4, 256, 0, stream>>>(ii_start, ii_e, gis0, gisA, I_N);
    spmm_pull_f32<<<(I_N + 3) / 4, 256, 0, stream>>>(ii_start, ii_e, gisA, gisB, I_N);

    // ---- ego: bufA(bf16) = [Gu; Gi]  (f32 ego stays in the input buffers) ----
    const int nu8 = (int)((size_t)U_N * KDIM / 8);
    const int ni8 = (int)(NI / 8);
    cvt_bf8<<<(nu8 + 255) / 256, 256, 0, stream>>>(Gu, bufA, nu8);
    cvt_bf8<<<(ni8 + 255) / 256, 256, 0, stream>>>(Gi, bufA + (size_t)U_N * KDIM, ni8);

    // ---- 3 UI layers; mean reconstructed in the final kernel ----
    spmm_pull_norm_noacc<<<(NR + 3) / 4, 256, 0, stream>>>(ui_start, ui_e, bufA, bufB, NR);
    spmm_pull_norm_noacc<<<(NR + 3) / 4, 256, 0, stream>>>(ui_start, ui_e, bufB, bufA, NR);
    spmm_pull_norm_final<<<(NR + 3) / 4, 256, 0, stream>>>(ui_start, ui_e, bufA, bufB,
                                                           Gu, Gi, gisB, out, NR);
}